// Round 14
// baseline (90.082 us; speedup 1.0000x reference)
//
#include <hip/hip_runtime.h>
#include <hip/hip_bf16.h>

#define NG 8
#define NT 4096
#define DIN 1024
#define DOUT 4096
#define BM 256
#define BN 128
#define BK 64
#define KTILES (DIN / BK)      // 16
#define NTILES (DOUT / BN)     // 32
#define RTILES (NT / BM + NG)  // 24
#define THREADS 512
#define ATILESZ (BM * BK * 2)  // 32KB bf16
#define BTILESZ (BN * BK * 2)  // 16KB bf16

typedef __attribute__((ext_vector_type(4))) float f32x4;
typedef __attribute__((ext_vector_type(8))) short bf16x8;

// async global->LDS, 16B/lane; dest = wave-uniform base + lane*16 (HW rule)
__device__ __forceinline__ void gld16(const void* g, void* l) {
    __builtin_amdgcn_global_load_lds(
        (const __attribute__((address_space(1))) void*)(g),
        (__attribute__((address_space(3))) void*)(l), 16, 0, 0);
}

// 4 f32 -> 8B packed bf16 (compiler emits v_cvt_pk_bf16_f32 pairs)
__device__ __forceinline__ unsigned long long pack4bf(f32x4 v) {
    union { __hip_bfloat16 h; unsigned short u; } c0, c1, c2, c3;
    c0.h = __float2bfloat16(v[0]);
    c1.h = __float2bfloat16(v[1]);
    c2.h = __float2bfloat16(v[2]);
    c3.h = __float2bfloat16(v[3]);
    return (unsigned long long)c0.u | ((unsigned long long)c1.u << 16) |
           ((unsigned long long)c2.u << 32) | ((unsigned long long)c3.u << 48);
}

// swizzled byte offset within a [rows][128B] bf16 tile (proven 0-conflict)
__device__ __forceinline__ int swz(int row, int colb) {
    return row * 128 + (colb ^ ((row & 7) << 4));
}

// ---- pass 1: x f32 -> bf16 workspace (~4-5us) ----
__global__ __launch_bounds__(256)
void cvt_x_kernel(const float* __restrict__ x, short* __restrict__ xb) {
    const int n4 = NT * DIN / 4;
    for (int i = blockIdx.x * blockDim.x + threadIdx.x; i < n4;
         i += gridDim.x * blockDim.x) {
        f32x4 v = ((const f32x4*)x)[i];
        ((unsigned long long*)xb)[i] = pack4bf(v);
    }
}

__global__ __launch_bounds__(THREADS, 2)
void grouped_gemm_8ph(const short* __restrict__ xb,
                      const int* __restrict__ offs,
                      const float* __restrict__ w,
                      float* __restrict__ out) {
    // A: dbuf bf16 [2][256][128B] = 64KB (DMA dest); B: dbuf bf16 [2][128][128B] = 32KB
    __shared__ char lds[2 * ATILESZ + 2 * BTILESZ];
    char* ldsA = lds;
    char* ldsB = lds + 2 * ATILESZ;

    // ---- map blockIdx.y -> (group, row0), group-aligned 256-row tiles ----
    const int rt = blockIdx.y;
    const int n0 = blockIdx.x * BN;
    int row0 = 0, endg = 0, gsel = -1;
    {
        int acc0 = 0, prev = 0;
        for (int g = 0; g < NG; ++g) {
            int e = offs[g];
            int cnt = (e - prev + BM - 1) / BM;
            if (rt < acc0 + cnt) { gsel = g; row0 = prev + (rt - acc0) * BM; endg = e; break; }
            acc0 += cnt; prev = e;
        }
    }
    if (gsel < 0) return;
    const float* wg = w + (size_t)gsel * DOUT * DIN;

    const int tid  = threadIdx.x;
    const int lane = tid & 63;
    const int wid  = tid >> 6;          // 0..7
    const int wrM  = wid >> 2;          // 0..1  (wave tile 128M x 32N)
    const int wcN  = wid & 3;           // 0..3
    const int lrow = lane & 15, kgrp = lane >> 4;

    // ---- A staging (R13-proven geometry): 32 stripes of 8 rows x 128B.
    //      wave wid covers stripes wid + i*8; lane -> row r = stripe*8+(lane>>3),
    //      dest chunk lane&7, SOURCE chunk (lane&7)^(r&7); frag read same XOR. ----
    int axoff[4], sbaseA[4];
    #pragma unroll
    for (int i = 0; i < 4; ++i) {
        int stripe = wid + i * 8;
        int r = stripe * 8 + (lane >> 3);
        int cs = (lane & 7) ^ (r & 7);
        int ar = row0 + r; if (ar >= endg) ar = endg - 1;   // clamp; masked at store
        axoff[i]  = ar * DIN + cs * 8;   // short units
        sbaseA[i] = stripe * 1024;       // bytes, wave-uniform
    }
    // ---- B staging: thread covers rows sr+i*32 (0..127), f32x4 col sc4 ----
    const int sr = tid >> 4, sc4 = tid & 15;
    int boff[4];
    #pragma unroll
    for (int i = 0; i < 4; ++i) boff[i] = (n0 + sr + i * 32) * DIN + sc4 * 4;

    f32x4 acc[8][2];
    #pragma unroll
    for (int m = 0; m < 8; ++m)
        #pragma unroll
        for (int n = 0; n < 2; ++n)
            acc[m][n] = (f32x4){0.f, 0.f, 0.f, 0.f};

    f32x4 pB[4];

    // ---- prologue: B(0) glb->cvt->write bufB[0]; A(0) DMA->bufA[0] ----
    #pragma unroll
    for (int i = 0; i < 4; ++i) pB[i] = *(const f32x4*)(wg + boff[i]);
    #pragma unroll
    for (int i = 0; i < 4; ++i) gld16(xb + axoff[i], ldsA + sbaseA[i]);
    #pragma unroll
    for (int i = 0; i < 4; ++i)   // compiler reg-dep vmcnt waits B(0) only
        *(unsigned long long*)(ldsB + swz(sr + i * 32, sc4 * 8)) = pack4bf(pB[i]);

    for (int kt = 0; kt < KTILES; ++kt) {
        const int cur = kt & 1;
        const char* lA = ldsA + cur * ATILESZ;
        const char* lB = ldsB + cur * BTILESZ;

        // ================= P0: issue next-tile loads, counted wait =================
        if (kt + 1 < KTILES) {
            const int k0 = (kt + 1) * BK;
            #pragma unroll
            for (int i = 0; i < 4; ++i) pB[i] = *(const f32x4*)(wg + boff[i] + k0);
            #pragma unroll
            for (int i = 0; i < 4; ++i)
                gld16(xb + axoff[i] + k0, ldsA + (cur ^ 1) * ATILESZ + sbaseA[i]);
            __builtin_amdgcn_sched_barrier(0);
            // 8 newer ops in flight (B 4 + A-DMA 4) -> waits exactly A-DMA(kt)
            asm volatile("s_waitcnt vmcnt(8) lgkmcnt(0)" ::: "memory");
        } else {
            __builtin_amdgcn_sched_barrier(0);
            asm volatile("s_waitcnt vmcnt(0) lgkmcnt(0)" ::: "memory");
        }
        __builtin_amdgcn_sched_barrier(0);
        __builtin_amdgcn_s_barrier();        // bufA[cur]/bufB[cur] complete+visible
        __builtin_amdgcn_sched_barrier(0);

        // phase 0: B frags (whole step) + A m0-1, 8 MFMA
        bf16x8 bb[2][2];
        {
            #pragma unroll
            for (int n = 0; n < 2; ++n)
                #pragma unroll
                for (int kk = 0; kk < 2; ++kk)
                    bb[n][kk] = *(const bf16x8*)(lB + swz(wcN * 32 + n * 16 + lrow,
                                                          kk * 64 + kgrp * 16));
            bf16x8 af[2][2];
            #pragma unroll
            for (int q = 0; q < 2; ++q)
                #pragma unroll
                for (int kk = 0; kk < 2; ++kk) {
                    int rA = wrM * 128 + q * 16 + lrow;
                    int kb = kk * 64 + kgrp * 16;
                    af[q][kk] = *(const bf16x8*)(lA + rA * 128 + ((((kb >> 4) ^ (rA & 7))) << 4));
                }
            asm volatile("s_waitcnt lgkmcnt(0)" ::: "memory");
            __builtin_amdgcn_sched_barrier(0);
            __builtin_amdgcn_s_setprio(1);
            #pragma unroll
            for (int q = 0; q < 2; ++q)
                #pragma unroll
                for (int n = 0; n < 2; ++n)
                    #pragma unroll
                    for (int kk = 0; kk < 2; ++kk)
                        acc[q][n] = __builtin_amdgcn_mfma_f32_16x16x32_bf16(
                            af[q][kk], bb[n][kk], acc[q][n], 0, 0, 0);
            __builtin_amdgcn_s_setprio(0);
            __builtin_amdgcn_s_barrier();
        }

        // phases 1..3: A m-quadrants; P3 also stages B(kt+1) into bufB[cur^1]
        #pragma unroll
        for (int p = 1; p < 4; ++p) {
            bf16x8 af[2][2];
            #pragma unroll
            for (int q = 0; q < 2; ++q)
                #pragma unroll
                for (int kk = 0; kk < 2; ++kk) {
                    int rA = wrM * 128 + (2 * p + q) * 16 + lrow;
                    int kb = kk * 64 + kgrp * 16;
                    af[q][kk] = *(const bf16x8*)(lA + rA * 128 + ((((kb >> 4) ^ (rA & 7))) << 4));
                }
            if (p == 3 && kt + 1 < KTILES) {
                // cvt (compiler reg-dep vmcnt(4) waits B(kt+1)) + ds_write
                #pragma unroll
                for (int i = 0; i < 4; ++i)
                    *(unsigned long long*)(ldsB + (cur ^ 1) * BTILESZ +
                                           swz(sr + i * 32, sc4 * 8)) = pack4bf(pB[i]);
            }
            __builtin_amdgcn_s_barrier();    // phase-begin (co-schedule waves)
            asm volatile("s_waitcnt lgkmcnt(0)" ::: "memory");
            __builtin_amdgcn_sched_barrier(0);
            __builtin_amdgcn_s_setprio(1);
            #pragma unroll
            for (int q = 0; q < 2; ++q)
                #pragma unroll
                for (int n = 0; n < 2; ++n)
                    #pragma unroll
                    for (int kk = 0; kk < 2; ++kk)
                        acc[2 * p + q][n] = __builtin_amdgcn_mfma_f32_16x16x32_bf16(
                            af[q][kk], bb[n][kk], acc[2 * p + q][n], 0, 0, 0);
            __builtin_amdgcn_s_setprio(0);
            __builtin_amdgcn_s_barrier();    // phase-end
        }
    }

    // ---- epilogue: C/D layout col=lane&15, row=(lane>>4)*4+j ----
    #pragma unroll
    for (int m = 0; m < 8; ++m) {
        #pragma unroll
        for (int j = 0; j < 4; ++j) {
            int row = row0 + wrM * 128 + m * 16 + kgrp * 4 + j;
            if (row < endg) {
                #pragma unroll
                for (int n = 0; n < 2; ++n) {
                    int col = n0 + wcN * 32 + n * 16 + lrow;
                    out[(size_t)row * DOUT + col] = acc[m][n][j];
                }
            }
        }
    }
}

extern "C" void kernel_launch(void* const* d_in, const int* in_sizes, int n_in,
                              void* d_out, int out_size, void* d_ws, size_t ws_size,
                              hipStream_t stream) {
    const float* x    = (const float*)d_in[0];
    const int*   offs = (const int*)d_in[1];
    const float* w    = (const float*)d_in[2];
    float* out = (float*)d_out;
    short* xb  = (short*)d_ws;   // NT*DIN bf16 = 8.4 MB

    cvt_x_kernel<<<1024, 256, 0, stream>>>(x, xb);
    dim3 grid(NTILES, RTILES, 1);
    grouped_gemm_8ph<<<grid, THREADS, 0, stream>>>(xb, offs, w, out);
}

// Round 15
// 71.051 us; speedup vs baseline: 1.2679x; 1.2679x over previous
//
#include <hip/hip_runtime.h>
#include <hip/hip_bf16.h>

#define NG 8
#define NT 4096
#define DIN 1024
#define DOUT 4096
#define BM 128
#define BN 128
#define BK 64
#define KTILES (DIN / BK)      // 16
#define NTILES (DOUT / BN)     // 32
#define RTILES (NT / BM + NG)  // 40
#define ATILESZ (BM * BK * 2)  // 16KB bf16
#define BTILESZ (BN * BK * 2)  // 16KB bf16

typedef __attribute__((ext_vector_type(4))) float f32x4;
typedef __attribute__((ext_vector_type(8))) short bf16x8;

// async global->LDS, 16B/lane; dest = wave-uniform base + lane*16 (HW rule)
__device__ __forceinline__ void gld16(const void* g, void* l) {
    __builtin_amdgcn_global_load_lds(
        (const __attribute__((address_space(1))) void*)(g),
        (__attribute__((address_space(3))) void*)(l), 16, 0, 0);
}

// 4 f32 -> 8B packed bf16 (compiler emits v_cvt_pk_bf16_f32 pairs)
__device__ __forceinline__ unsigned long long pack4bf(f32x4 v) {
    union { __hip_bfloat16 h; unsigned short u; } c0, c1, c2, c3;
    c0.h = __float2bfloat16(v[0]);
    c1.h = __float2bfloat16(v[1]);
    c2.h = __float2bfloat16(v[2]);
    c3.h = __float2bfloat16(v[3]);
    return (unsigned long long)c0.u | ((unsigned long long)c1.u << 16) |
           ((unsigned long long)c2.u << 32) | ((unsigned long long)c3.u << 48);
}

// swizzled byte offset within a [rows][128B] bf16 tile (proven 0-conflict)
__device__ __forceinline__ int swz(int row, int colb) {
    return row * 128 + (colb ^ ((row & 7) << 4));
}

// ---- pass 1: x f32 -> bf16 workspace (~4-5us) ----
__global__ __launch_bounds__(256)
void cvt_x_kernel(const float* __restrict__ x, short* __restrict__ xb) {
    const int n4 = NT * DIN / 4;
    for (int i = blockIdx.x * blockDim.x + threadIdx.x; i < n4;
         i += gridDim.x * blockDim.x) {
        f32x4 v = ((const f32x4*)x)[i];
        ((unsigned long long*)xb)[i] = pack4bf(v);
    }
}

__global__ __launch_bounds__(256, 2)
void grouped_gemm_bf16(const short* __restrict__ xb,
                       const int* __restrict__ offs,
                       const float* __restrict__ w,
                       float* __restrict__ out) {
    // A: dbuf bf16 [2][128][128B] = 32KB (DMA dest, linear)
    // B: single bf16 [128][128B] = 16KB (reg-staged f32 + cvt)  -> 48KB total
    __shared__ char lds[2 * ATILESZ + BTILESZ];
    char* ldsA = lds;
    char* ldsB = lds + 2 * ATILESZ;

    // ---- map blockIdx.y -> (group, row0), group-aligned 128-row tiles ----
    const int rt = blockIdx.y;
    const int n0 = blockIdx.x * BN;
    int row0 = 0, endg = 0, gsel = -1;
    {
        int acc0 = 0, prev = 0;
        for (int g = 0; g < NG; ++g) {
            int e = offs[g];
            int cnt = (e - prev + BM - 1) / BM;
            if (rt < acc0 + cnt) { gsel = g; row0 = prev + (rt - acc0) * BM; endg = e; break; }
            acc0 += cnt; prev = e;
        }
    }
    if (gsel < 0) return;
    const float* wg = w + (size_t)gsel * DOUT * DIN;

    const int tid  = threadIdx.x;
    const int lane = tid & 63;
    const int wid  = tid >> 6;
    const int wr   = wid >> 1, wc = wid & 1;     // 2x2 wave grid, wave tile 64x64
    const int lrow = lane & 15, kgrp = lane >> 4;

    // ---- A staging (R13-proven geometry): 16 stripes of 8 rows x 128B.
    //      wave wid covers stripe = i*4+wid; lane -> row r = stripe*8+(lane>>3),
    //      dest chunk lane&7 (linear), SOURCE chunk (lane&7)^(r&7);
    //      frag read applies the same XOR. ----
    int axoff[4], sbaseA[4];
    #pragma unroll
    for (int i = 0; i < 4; ++i) {
        int stripe = i * 4 + wid;
        int r = stripe * 8 + (lane >> 3);
        int cs = (lane & 7) ^ (r & 7);
        int ar = row0 + r; if (ar >= endg) ar = endg - 1;   // clamp; masked at store
        axoff[i]  = ar * DIN + cs * 8;   // short units (8 shorts = 16B)
        sbaseA[i] = stripe * 1024;       // bytes, wave-uniform
    }
    // ---- B staging: thread covers rows sr+i*16 (0..127), f32x4 col sc4 ----
    const int sr = tid >> 4, sc4 = tid & 15;
    int boff[8];
    #pragma unroll
    for (int i = 0; i < 8; ++i) boff[i] = (n0 + sr + i * 16) * DIN + sc4 * 4;

    f32x4 acc[4][4];
    #pragma unroll
    for (int m = 0; m < 4; ++m)
        #pragma unroll
        for (int n = 0; n < 4; ++n)
            acc[m][n] = (f32x4){0.f, 0.f, 0.f, 0.f};

    f32x4 pB[8];

    // ---- prologue: B(0) loads + A(0) DMA; cvt+write B(0) (reg-dep vmcnt) ----
    #pragma unroll
    for (int i = 0; i < 8; ++i) pB[i] = *(const f32x4*)(wg + boff[i]);
    #pragma unroll
    for (int i = 0; i < 4; ++i) gld16(xb + axoff[i], ldsA + sbaseA[i]);
    #pragma unroll
    for (int i = 0; i < 8; ++i)   // compiler waits B(0) via reg deps, not the DMA
        *(unsigned long long*)(ldsB + swz(sr + i * 16, sc4 * 8)) = pack4bf(pB[i]);

    for (int kt = 0; kt < KTILES; ++kt) {
        const int cur = kt & 1;
        const char* lA = ldsA + cur * ATILESZ;

        // ---- P0: issue next-tile loads (B->regs, A->DMA into bufA[cur^1]),
        //      then counted wait: 12 newer ops (8 B + 4 DMA) -> drains exactly
        //      A-DMA(kt); lgkm(0) retires last step's B ds_writes. ----
        if (kt + 1 < KTILES) {
            const int k0 = (kt + 1) * BK;
            #pragma unroll
            for (int i = 0; i < 8; ++i) pB[i] = *(const f32x4*)(wg + boff[i] + k0);
            #pragma unroll
            for (int i = 0; i < 4; ++i)
                gld16(xb + axoff[i] + k0, ldsA + (cur ^ 1) * ATILESZ + sbaseA[i]);
            __builtin_amdgcn_sched_barrier(0);
            asm volatile("s_waitcnt vmcnt(12) lgkmcnt(0)" ::: "memory");
        } else {
            __builtin_amdgcn_sched_barrier(0);
            asm volatile("s_waitcnt vmcnt(0) lgkmcnt(0)" ::: "memory");
        }
        __builtin_amdgcn_sched_barrier(0);
        __builtin_amdgcn_s_barrier();    // bufA[cur] + bufB(kt) visible to all
        __builtin_amdgcn_sched_barrier(0);

        // ---- compute tile kt: A frags direct-XOR, B frags swz ----
        __builtin_amdgcn_s_setprio(1);
        #pragma unroll
        for (int kk = 0; kk < 2; ++kk) {
            const int kb = kk * 64 + kgrp * 16;
            bf16x8 af[4], bb[4];
            #pragma unroll
            for (int m = 0; m < 4; ++m) {
                int r = wr * 64 + m * 16 + lrow;
                af[m] = *(const bf16x8*)(lA + r * 128 + (((kb >> 4) ^ (r & 7)) << 4));
            }
            #pragma unroll
            for (int n = 0; n < 4; ++n)
                bb[n] = *(const bf16x8*)(ldsB + swz(wc * 64 + n * 16 + lrow, kb));
            #pragma unroll
            for (int m = 0; m < 4; ++m)
                #pragma unroll
                for (int n = 0; n < 4; ++n)
                    acc[m][n] = __builtin_amdgcn_mfma_f32_16x16x32_bf16(
                        af[m], bb[n], acc[m][n], 0, 0, 0);
        }
        __builtin_amdgcn_s_setprio(0);

        // ---- barrier-2 (B readers done), then cvt+write B(kt+1); the next
        //      step's P0 wait+barrier provide retirement+visibility ----
        if (kt + 1 < KTILES) {
            __builtin_amdgcn_sched_barrier(0);
            __builtin_amdgcn_s_barrier();
            __builtin_amdgcn_sched_barrier(0);
            #pragma unroll
            for (int i = 0; i < 8; ++i)   // reg-dep vmcnt(4) waits B(kt+1) only
                *(unsigned long long*)(ldsB + swz(sr + i * 16, sc4 * 8)) = pack4bf(pB[i]);
        }
    }

    // ---- epilogue: C/D layout col=lane&15, row=(lane>>4)*4+j ----
    #pragma unroll
    for (int m = 0; m < 4; ++m) {
        #pragma unroll
        for (int j = 0; j < 4; ++j) {
            int row = row0 + wr * 64 + m * 16 + kgrp * 4 + j;
            if (row < endg) {
                #pragma unroll
                for (int n = 0; n < 4; ++n) {
                    int col = n0 + wc * 64 + n * 16 + lrow;
                    out[(size_t)row * DOUT + col] = acc[m][n][j];
                }
            }
        }
    }
}

extern "C" void kernel_launch(void* const* d_in, const int* in_sizes, int n_in,
                              void* d_out, int out_size, void* d_ws, size_t ws_size,
                              hipStream_t stream) {
    const float* x    = (const float*)d_in[0];
    const int*   offs = (const int*)d_in[1];
    const float* w    = (const float*)d_in[2];
    float* out = (float*)d_out;
    short* xb  = (short*)d_ws;   // NT*DIN bf16 = 8.4 MB

    cvt_x_kernel<<<1024, 256, 0, stream>>>(x, xb);
    dim3 grid(NTILES, RTILES, 1);
    grouped_gemm_bf16<<<grid, 256, 0, stream>>>(xb, offs, w, out);
}